// Round 10
// baseline (297.838 us; speedup 1.0000x reference)
//
#include <hip/hip_runtime.h>
#include <hip/hip_bf16.h>
#include <math.h>

// Problem constants
#define BATCH 4
#define SEQ   2048
#define CDIM  1024
#define NHEAD 16
#define HDIM  64
#define QKVN  3072
#define QSCALE 0.1803368801111244f   // 0.125 * log2(e); softmax done in exp2 domain

typedef float f32x4 __attribute__((ext_vector_type(4)));
typedef float f32x16 __attribute__((ext_vector_type(16)));
typedef short bf16x8 __attribute__((ext_vector_type(8)));
typedef short bf16x4 __attribute__((ext_vector_type(4)));
typedef int i32x2 __attribute__((ext_vector_type(2)));
typedef int i32x4 __attribute__((ext_vector_type(4)));

static __device__ __forceinline__ unsigned short f2bf(float f) {
    unsigned int u = __float_as_uint(f);
    u += 0x7FFF + ((u >> 16) & 1);   // RNE
    return (unsigned short)(u >> 16);
}
static __device__ __forceinline__ float bf2f(unsigned short u) {
    return __uint_as_float(((unsigned int)u) << 16);
}
static __device__ __forceinline__ unsigned int pk2bf(float lo, float hi) {
    __hip_bfloat162 h = __float22bfloat162_rn(make_float2(lo, hi));
    return *(unsigned int*)&h;
}
// 16-byte LDS read as two 8B halves (pitch-68 rows are only 8B aligned)
static __device__ __forceinline__ bf16x8 lds_read8(const unsigned short* p) {
    bf16x4 lo = *(const bf16x4*)p;
    bf16x4 hi = *(const bf16x4*)(p + 4);
    return __builtin_shufflevector(lo, hi, 0, 1, 2, 3, 4, 5, 6, 7);
}

// ---------------- consolidated prep: ctab + x->bf16 + both W transposes ------
static __device__ __forceinline__ void transpose_tile(
    const float* __restrict__ W, unsigned short* __restrict__ Wt,
    int K, int N, int bx, int by, unsigned short (*tile)[65], int tid) {
    const int n0 = bx * 64;
    const int k0 = by * 64;
    const int r = tid >> 4;
    const int c4 = (tid & 15) << 2;
    #pragma unroll
    for (int ii = 0; ii < 4; ii++) {
        int row = r + 16 * ii;
        float4 v = *(const float4*)&W[(size_t)(k0 + row) * N + n0 + c4];
        tile[c4 + 0][row] = f2bf(v.x);
        tile[c4 + 1][row] = f2bf(v.y);
        tile[c4 + 2][row] = f2bf(v.z);
        tile[c4 + 3][row] = f2bf(v.w);
    }
    __syncthreads();
    #pragma unroll
    for (int ii = 0; ii < 4; ii++) {
        int row = r + 16 * ii;
        ushort4 o;
        o.x = tile[row][c4 + 0];
        o.y = tile[row][c4 + 1];
        o.z = tile[row][c4 + 2];
        o.w = tile[row][c4 + 3];
        *(ushort4*)&Wt[(size_t)(n0 + row) * K + k0 + c4] = o;
    }
}

__global__ __launch_bounds__(256) void prep(
    const float* __restrict__ x, const float* __restrict__ W_qkv,
    const float* __restrict__ W_out, float2* __restrict__ ctab,
    unsigned short* __restrict__ xb, unsigned short* __restrict__ wqb,
    unsigned short* __restrict__ wob) {
    __shared__ unsigned short tile[64][65];
    const int blk = blockIdx.x;
    const int tid = threadIdx.x;
    if (blk < 8192) {
        // x fp32 -> xb bf16, 2,097,152 float4s
        const int i = blk * 256 + tid;
        float4 v = ((const float4*)x)[i];
        ushort4 o;
        o.x = f2bf(v.x); o.y = f2bf(v.y); o.z = f2bf(v.z); o.w = f2bf(v.w);
        ((ushort4*)xb)[i] = o;
    } else if (blk < 8448) {
        // RoPE table: ctab[t*32+dp] = (cos, sin), 65536 entries
        const int i = (blk - 8192) * 256 + tid;
        const int dp = i & 31;
        const int t = i >> 5;
        const float invf = powf(10000.0f, -((float)(2 * dp)) / 64.0f);
        float sv, cv;
        __sincosf((float)t * invf, &sv, &cv);
        ctab[i] = make_float2(cv, sv);
    } else if (blk < 9216) {
        // W_qkv [1024][3072] -> wqb [3072][1024], dim3(48,16)
        const int r = blk - 8448;
        transpose_tile(W_qkv, wqb, CDIM, QKVN, r % 48, r / 48, tile, tid);
    } else {
        // W_out [1024][1024] -> wob [1024][1024]^T, dim3(16,16)
        const int r = blk - 9216;
        transpose_tile(W_out, wob, CDIM, CDIM, r % 16, r / 16, tile, tid);
    }
}

#define GLDS(gp, lp) __builtin_amdgcn_global_load_lds(                       \
    (const __attribute__((address_space(1))) unsigned int*)(gp),             \
    (__attribute__((address_space(3))) unsigned int*)(lp), 16, 0, 0)

// ---------------- bf16 MFMA GEMM, BK=64: C = A[M,K] @ Bt[N,K]^T --------------
// R10: K-step 32 -> 64. Same bytes staged, HALF the barrier-drain events (the
// measured m97-stall: MfmaUtil 22 / VALUBusy 17 / nothing busy). The two
// 32-wide slices are consumed SEQUENTIALLY from one staged buffer so live
// fragment registers don't grow (R8's dbuf mistake). LDS 16->32KB: occupancy
// still VGPR-capped at 4 blocks/CU (LDS cap 5), unchanged.
// Bank swizzle for the 128x64 tile (row stride 128B == 32 banks exactly):
// LDS slot sl of row r holds global chunk c = sl ^ (r&7); staging pre-permutes
// the per-lane GLOBAL chunk (GLDS dest stays lane-contiguous); reads use
// sl = (ks*4+quad) ^ (fm&7) -> 8 lanes/slot = 2 lanes/bank = free.
template <typename OUT>
__global__ __launch_bounds__(256) void gemm_bt_bf16(
    const unsigned short* __restrict__ A,
    const unsigned short* __restrict__ Bt,
    OUT* __restrict__ C, int M, int N, int K) {
    __shared__ unsigned short As[128 * 64];
    __shared__ unsigned short Bs[128 * 64];

    const int tid = threadIdx.x;
    const int wave = tid >> 6;
    const int lane = tid & 63;
    const int bm = blockIdx.y * 128;
    const int bn = blockIdx.x * 128;
    const int wm = (wave >> 1) * 64;
    const int wn = (wave & 1) * 64;

    // staging: lane covers row (bm + sr + 32*ii), global chunk (tid&7)^(sr&7)
    const int sr = tid >> 3;
    const int sc = ((tid & 7) ^ (sr & 7)) << 3;
    const unsigned short* Ag = A + (size_t)(bm + sr) * K + sc;
    const unsigned short* Bg = Bt + (size_t)(bn + sr) * K + sc;
    char* AsW = (char*)As + wave * 1024;
    char* BsW = (char*)Bs + wave * 1024;

    const int fm = lane & 15;
    const int quad = lane >> 4;
    const int sl0 = ((quad ^ (fm & 7)) << 3);        // ks=0 slot (elem offset)
    const int sl1 = (((4 + quad) ^ (fm & 7)) << 3);  // ks=1 slot

    f32x4 acc[4][4];
    #pragma unroll
    for (int i = 0; i < 4; i++)
        #pragma unroll
        for (int j = 0; j < 4; j++)
            acc[i][j] = (f32x4){0.f, 0.f, 0.f, 0.f};

    for (int k0 = 0; k0 < K; k0 += 64) {
        GLDS(Ag + k0, AsW);
        GLDS(Ag + 32 * K + k0, AsW + 4096);
        GLDS(Ag + 64 * K + k0, AsW + 8192);
        GLDS(Ag + 96 * K + k0, AsW + 12288);
        GLDS(Bg + k0, BsW);
        GLDS(Bg + 32 * K + k0, BsW + 4096);
        GLDS(Bg + 64 * K + k0, BsW + 8192);
        GLDS(Bg + 96 * K + k0, BsW + 12288);
        __syncthreads();

        bf16x8 af[4], bfr[4];
        // ---- ks = 0 slice ----
        #pragma unroll
        for (int i = 0; i < 4; i++)
            af[i] = *(const bf16x8*)&As[(wm + i * 16 + fm) * 64 + sl0];
        #pragma unroll
        for (int j = 0; j < 4; j++)
            bfr[j] = *(const bf16x8*)&Bs[(wn + j * 16 + fm) * 64 + sl0];
        #pragma unroll
        for (int i = 0; i < 4; i++)
            #pragma unroll
            for (int j = 0; j < 4; j++)
                acc[i][j] = __builtin_amdgcn_mfma_f32_16x16x32_bf16(
                    af[i], bfr[j], acc[i][j], 0, 0, 0);
        // ---- ks = 1 slice ----
        #pragma unroll
        for (int i = 0; i < 4; i++)
            af[i] = *(const bf16x8*)&As[(wm + i * 16 + fm) * 64 + sl1];
        #pragma unroll
        for (int j = 0; j < 4; j++)
            bfr[j] = *(const bf16x8*)&Bs[(wn + j * 16 + fm) * 64 + sl1];
        #pragma unroll
        for (int i = 0; i < 4; i++)
            #pragma unroll
            for (int j = 0; j < 4; j++)
                acc[i][j] = __builtin_amdgcn_mfma_f32_16x16x32_bf16(
                    af[i], bfr[j], acc[i][j], 0, 0, 0);
        __syncthreads();
    }

    const int er = quad * 4;
    #pragma unroll
    for (int i = 0; i < 4; i++) {
        #pragma unroll
        for (int j = 0; j < 4; j++) {
            #pragma unroll
            for (int r = 0; r < 4; r++) {
                size_t off = (size_t)(bm + wm + i * 16 + er + r) * N + bn + wn + j * 16 + fm;
                if constexpr (sizeof(OUT) == 2)
                    C[off] = f2bf(acc[i][j][r]);
                else
                    C[off] = acc[i][j][r];
            }
        }
    }
}

// ---------------- fused qkv GEMM (BK=64): RoPE(q,k) / V-transpose epilogue ---
// Same BK=64 loop as gemm_bt_bf16; flat SH (32KB) so the epilogue can overlay
// its [64][132] transpose tile. Epilogue unchanged from R7 (measured-good).
__global__ __launch_bounds__(256) void gemm_qkv_fused(
    const unsigned short* __restrict__ A,     // xb [8192][1024]
    const unsigned short* __restrict__ Bt,    // wqb [3072][1024]
    const float2* __restrict__ ctab,          // [2048][32]
    unsigned short* __restrict__ Qg,
    unsigned short* __restrict__ Kg,
    unsigned short* __restrict__ Vtg) {
    __shared__ unsigned short SH[16384];      // loop: As=SH[0:8192), Bs=SH[8192:16384)
                                              // epilogue: [64][132] bf16 tile
    unsigned short* As = SH;
    unsigned short* Bs = SH + 8192;
    const int K = CDIM;

    const int tid = threadIdx.x;
    const int wave = tid >> 6;
    const int lane = tid & 63;
    const int bm = blockIdx.y * 128;
    const int bn = blockIdx.x * 128;
    const int wm = (wave >> 1) * 64;
    const int wn = (wave & 1) * 64;

    const int sr = tid >> 3;
    const int sc = ((tid & 7) ^ (sr & 7)) << 3;
    const unsigned short* Ag = A + (size_t)(bm + sr) * K + sc;
    const unsigned short* Bg = Bt + (size_t)(bn + sr) * K + sc;
    char* AsW = (char*)SH + wave * 1024;
    char* BsW = (char*)SH + 16384 + wave * 1024;   // byte offset of Bs

    const int fm = lane & 15;
    const int quad = lane >> 4;
    const int sl0 = ((quad ^ (fm & 7)) << 3);
    const int sl1 = (((4 + quad) ^ (fm & 7)) << 3);

    f32x4 acc[4][4];
    #pragma unroll
    for (int i = 0; i < 4; i++)
        #pragma unroll
        for (int j = 0; j < 4; j++)
            acc[i][j] = (f32x4){0.f, 0.f, 0.f, 0.f};

    for (int k0 = 0; k0 < K; k0 += 64) {
        GLDS(Ag + k0, AsW);
        GLDS(Ag + 32 * K + k0, AsW + 4096);
        GLDS(Ag + 64 * K + k0, AsW + 8192);
        GLDS(Ag + 96 * K + k0, AsW + 12288);
        GLDS(Bg + k0, BsW);
        GLDS(Bg + 32 * K + k0, BsW + 4096);
        GLDS(Bg + 64 * K + k0, BsW + 8192);
        GLDS(Bg + 96 * K + k0, BsW + 12288);
        __syncthreads();

        bf16x8 af[4], bfr[4];
        #pragma unroll
        for (int i = 0; i < 4; i++)
            af[i] = *(const bf16x8*)&As[(wm + i * 16 + fm) * 64 + sl0];
        #pragma unroll
        for (int j = 0; j < 4; j++)
            bfr[j] = *(const bf16x8*)&Bs[(wn + j * 16 + fm) * 64 + sl0];
        #pragma unroll
        for (int i = 0; i < 4; i++)
            #pragma unroll
            for (int j = 0; j < 4; j++)
                acc[i][j] = __builtin_amdgcn_mfma_f32_16x16x32_bf16(
                    af[i], bfr[j], acc[i][j], 0, 0, 0);
        #pragma unroll
        for (int i = 0; i < 4; i++)
            af[i] = *(const bf16x8*)&As[(wm + i * 16 + fm) * 64 + sl1];
        #pragma unroll
        for (int j = 0; j < 4; j++)
            bfr[j] = *(const bf16x8*)&Bs[(wn + j * 16 + fm) * 64 + sl1];
        #pragma unroll
        for (int i = 0; i < 4; i++)
            #pragma unroll
            for (int j = 0; j < 4; j++)
                acc[i][j] = __builtin_amdgcn_mfma_f32_16x16x32_bf16(
                    af[i], bfr[j], acc[i][j], 0, 0, 0);
        __syncthreads();
    }

    // ---------------- fused epilogue (unchanged from R7) ----------------
    const int s = bn >> 10;                  // 0=q, 1=k, 2=v (128-col tile never straddles)
    const int hbase = (bn & 1023) >> 6;      // block covers heads hbase, hbase+1
    const int b = bm >> 11;                  // 128-row tile never straddles batch
    const int t0 = bm & 2047;

    #pragma unroll 1
    for (int pass = 0; pass < 2; pass++) {
        // waves whose rows are in this half write their acc tile to SH [64][132]
        if ((wave >> 1) == pass) {
            #pragma unroll
            for (int i = 0; i < 4; i++)
                #pragma unroll
                for (int j = 0; j < 4; j++)
                    #pragma unroll
                    for (int r = 0; r < 4; r++)
                        SH[(i * 16 + quad * 4 + r) * 132 + wn + j * 16 + fm] =
                            f2bf(acc[i][j][r]);
        }
        __syncthreads();

        if (s < 2) {
            unsigned short* dst = (s == 0) ? Qg : Kg;
            const float sc2 = (s == 0) ? QSCALE : 1.0f;
            #pragma unroll
            for (int it = 0; it < 16; it++) {
                const int idx = it * 256 + tid;      // 64 rows x 64 col-pairs
                const int row = idx >> 6;
                const int col = (idx & 63) << 1;
                const unsigned int pr = *(const unsigned int*)&SH[row * 132 + col];
                const float x0 = bf2f((unsigned short)pr);
                const float x1 = bf2f((unsigned short)(pr >> 16));
                const int t = t0 + pass * 64 + row;
                const int h = hbase + (col >> 6);
                const int d = col & 63;
                const float2 cs = ctab[t * 32 + (d >> 1)];
                const float r0 = (x0 * cs.x - x1 * cs.y) * sc2;
                const float r1 = (x1 * cs.x + x0 * cs.y) * sc2;
                *(unsigned int*)&dst[((size_t)(b * NHEAD + h) * SEQ + t) * HDIM + d] =
                    pk2bf(r0, r1);
            }
        } else {
            #pragma unroll
            for (int it = 0; it < 8; it++) {
                const int idx = it * 256 + tid;      // 128 cols x 16 t-chunks
                const int dcol = idx >> 4;
                const int tq = idx & 15;
                ushort4 o;
                o.x = SH[(tq * 4 + 0) * 132 + dcol];
                o.y = SH[(tq * 4 + 1) * 132 + dcol];
                o.z = SH[(tq * 4 + 2) * 132 + dcol];
                o.w = SH[(tq * 4 + 3) * 132 + dcol];
                const int h = hbase + (dcol >> 6);
                const int dl = dcol & 63;
                const int t = t0 + pass * 64 + tq * 4;
                *(ushort4*)&Vtg[((size_t)(b * NHEAD + h) * HDIM + dl) * SEQ + t] = o;
            }
        }
        __syncthreads();
    }
}

// ---------------- MFMA flash attention: in-register P (T12), 32x32 MFMAs ----
// R6 (passed): R0 residency (4 blocks/CU) + dbuf 1-barrier schedule +
// swapped-QK^T in-register softmax (cvt_pk + permlane32_swap, no Ps LDS).
__global__ __launch_bounds__(256, 4) void flash_attn_mfma(
    const unsigned short* __restrict__ Qg,
    const unsigned short* __restrict__ Kg,
    const unsigned short* __restrict__ Vtg,
    unsigned short* __restrict__ att) {
    __shared__ unsigned short Ks[2][64 * 68];   // [buf][key][d]
    __shared__ unsigned short Vt[2][64 * 68];   // [buf][d][key]

    const int tid = threadIdx.x;
    const int wave = tid >> 6;
    const int lane = tid & 63;
    const int l31 = lane & 31;
    const int hi = lane >> 5;
    const int wq = wave * 32;
    const int bh = blockIdx.x & 63;          // blk%8==bh%8 -> bh's blocks share an XCD
    const int qt = 15 - (blockIdx.x >> 6);   // heavy Q-tiles first
    const int b = bh >> 4, h = bh & 15;

    const int r_ld = tid >> 4;
    const int c4 = (tid & 15) << 2;

    const unsigned short* Kbase = Kg + (size_t)bh * SEQ * HDIM;
    const unsigned short* Vbase = Vtg + (size_t)bh * HDIM * SEQ;

    const int qrow = qt * 128 + wq + l31;    // this lane's q column

    // Q B-fragments (n=l31=q, k=d chunk dc*16 + hi*8): 4 x 16B from global
    bf16x8 bq[4];
    #pragma unroll
    for (int dc = 0; dc < 4; dc++)
        bq[dc] = *(const bf16x8*)&Qg[((size_t)bh * SEQ + qrow) * HDIM + dc * 16 + hi * 8];

    f32x16 O[2];
    #pragma unroll
    for (int nt = 0; nt < 2; nt++)
        #pragma unroll
        for (int r = 0; r < 16; r++) O[nt][r] = 0.f;
    float lsum = 0.f;

    const int jtop = 2 * qt + 1;

    // ---- prologue: stage tile 0 into buffer 0 ----
    ushort4 kreg[4], vreg[4];
    #pragma unroll
    for (int ii = 0; ii < 4; ii++) {
        const int row = r_ld + 16 * ii;
        kreg[ii] = *(const ushort4*)&Kbase[(size_t)row * HDIM + c4];
        vreg[ii] = *(const ushort4*)&Vbase[(size_t)row * SEQ + c4];
    }
    #pragma unroll
    for (int ii = 0; ii < 4; ii++) {
        const int row = r_ld + 16 * ii;
        *(ushort4*)&Ks[0][row * 68 + c4] = kreg[ii];
        *(ushort4*)&Vt[0][row * 68 + c4] = vreg[ii];
    }
    __syncthreads();

    int cur = 0;
    #pragma unroll 1
    for (int j = 0; j <= jtop; j++) {
        // (A) issue next tile's global loads now; consumed at (C) after compute
        if (j < jtop) {
            #pragma unroll
            for (int ii = 0; ii < 4; ii++) {
                const int row = r_ld + 16 * ii;
                kreg[ii] = *(const ushort4*)&Kbase[(size_t)((j + 1) * 64 + row) * HDIM + c4];
                vreg[ii] = *(const ushort4*)&Vbase[(size_t)row * SEQ + (j + 1) * 64 + c4];
            }
        }

        // (B) compute tile j from buffer cur
        const bool active = (j * 64) <= (qt * 128 + wq + 31);
        if (active) {
            const unsigned short* Kc = Ks[cur];
            const unsigned short* Vc = Vt[cur];
            const bool diag = (j * 64 + 63) > (qt * 128 + wq);

            #pragma unroll
            for (int kt = 0; kt < 2; kt++) {
                // ---- S^T = K Q^T : D[k][q], lane col q=l31 ----
                f32x16 sa;
                #pragma unroll
                for (int r = 0; r < 16; r++) sa[r] = 0.f;
                __builtin_amdgcn_s_setprio(1);
                #pragma unroll
                for (int dc = 0; dc < 4; dc++) {
                    bf16x8 ak = lds_read8(&Kc[(kt * 32 + l31) * 68 + dc * 16 + hi * 8]);
                    sa = __builtin_amdgcn_mfma_f32_32x32x16_bf16(ak, bq[dc], sa, 0, 0, 0);
                }
                __builtin_amdgcn_s_setprio(0);

                // ---- causal mask (diagonal tiles only): k_glob > q ----
                if (diag) {
                    const int kb = j * 64 + kt * 32 + 4 * hi;
                    #pragma unroll
                    for (int r = 0; r < 16; r++) {
                        const int kg = kb + (r & 3) + 8 * (r >> 2);
                        if (kg > qrow) sa[r] = -INFINITY;
                    }
                }

                // ---- P = exp2(S), per-lane row-sum partial, pack to bf16 ----
                float e[16];
                #pragma unroll
                for (int r = 0; r < 16; r++) {
                    e[r] = exp2f(sa[r]);
                    lsum += e[r];
                }
                unsigned int p32[8];
                #pragma unroll
                for (int v = 0; v < 8; v++)
                    p32[v] = pk2bf(e[2 * v], e[2 * v + 1]);

                // ---- permlane32_swap -> PV A-frags; O += P @ V ----
                #pragma unroll
                for (int c = 0; c < 2; c++) {
                    i32x2 s0 = __builtin_amdgcn_permlane32_swap(
                        (int)p32[4 * c + 0], (int)p32[4 * c + 2], false, false);
                    i32x2 s1 = __builtin_amdgcn_permlane32_swap(
                        (int)p32[4 * c + 1], (int)p32[4 * c + 3], false, false);
                    i32x4 pw = (i32x4){s0[0], s1[0], s0[1], s1[1]};
                    bf16x8 pa = *(bf16x8*)&pw;
                    __builtin_amdgcn_s_setprio(1);
                    #pragma unroll
                    for (int nt = 0; nt < 2; nt++) {
                        bf16x8 bv = lds_read8(&Vc[(nt * 32 + l31) * 68 + kt * 32 + c * 16 + hi * 8]);
                        O[nt] = __builtin_amdgcn_mfma_f32_32x32x16_bf16(pa, bv, O[nt], 0, 0, 0);
                    }
                    __builtin_amdgcn_s_setprio(0);
                }
            }
        }

        // (C) write tile j+1 into the idle buffer (vmcnt waits here, a full
        //     compute phase after issue)
        if (j < jtop) {
            const int nb = cur ^ 1;
            #pragma unroll
            for (int ii = 0; ii < 4; ii++) {
                const int row = r_ld + 16 * ii;
                *(ushort4*)&Ks[nb][row * 68 + c4] = kreg[ii];
                *(ushort4*)&Vt[nb][row * 68 + c4] = vreg[ii];
            }
        }

        // (D) one barrier per iteration
        __syncthreads();
        cur ^= 1;
    }

    // ---- epilogue: complete l (partner half), broadcast to O rows, store ----
    const float lfull = lsum + __shfl_xor(lsum, 32);
    const float inv = 1.0f / lfull;          // valid at lanes q and q+32
    #pragma unroll
    for (int r = 0; r < 16; r++) {
        const int qloc = (r & 3) + 8 * (r >> 2) + 4 * hi;   // O row within 32
        const float invr = __uint_as_float((unsigned int)__builtin_amdgcn_ds_bpermute(
            qloc * 4, (int)__float_as_uint(inv)));
        const int row = qt * 128 + wq + qloc;
        #pragma unroll
        for (int nt = 0; nt < 2; nt++)
            att[(size_t)(b * SEQ + row) * CDIM + h * HDIM + nt * 32 + l31] =
                f2bf(O[nt][r] * invr);
    }
}

extern "C" void kernel_launch(void* const* d_in, const int* in_sizes, int n_in,
                              void* d_out, int out_size, void* d_ws, size_t ws_size,
                              hipStream_t stream) {
    const float* x     = (const float*)d_in[0];
    const float* W_qkv = (const float*)d_in[1];
    const float* W_out = (const float*)d_in[2];
    float* out = (float*)d_out;

    const int M = BATCH * SEQ;   // 8192

    // workspace layout (~92 MB)
    float2* ctab = (float2*)d_ws;                               // 2048*32 float2
    unsigned short* xb   = (unsigned short*)(ctab + SEQ * 32);  // M*1024 bf16
    unsigned short* wqb  = xb + (size_t)M * CDIM;               // 3072*1024
    unsigned short* wob  = wqb + (size_t)CDIM * QKVN;           // 1024*1024
    unsigned short* attb = wob + (size_t)CDIM * CDIM;           // M*1024
    unsigned short* Qg   = attb + (size_t)M * CDIM;             // [bh][t][d]
    unsigned short* Kg   = Qg + (size_t)M * CDIM;
    unsigned short* Vtg  = Kg + (size_t)M * CDIM;               // [bh][d][t]

    // 1) consolidated prep: ctab + x->bf16 + W transposes (one launch)
    prep<<<9472, 256, 0, stream>>>(x, W_qkv, W_out, ctab, xb, wqb, wob);

    // 2) fused qkv GEMM (BK=64, R10): writes Qg/Kg/Vtg
    gemm_qkv_fused<<<dim3(QKVN / 128, M / 128), 256, 0, stream>>>(
        xb, wqb, ctab, Qg, Kg, Vtg);

    // 3) MFMA flash attention: in-register P, 32x32 MFMAs, dbuf 1-barrier (R6)
    flash_attn_mfma<<<BATCH * NHEAD * (SEQ / 128), 256, 0, stream>>>(Qg, Kg, Vtg, attb);

    // 4) out = att @ W_out (BK=64, fp32 out)
    gemm_bt_bf16<float><<<dim3(CDIM / 128, M / 128), 256, 0, stream>>>(
        attb, wob, out, M, CDIM, CDIM);
}

// Round 11
// 270.434 us; speedup vs baseline: 1.1013x; 1.1013x over previous
//
#include <hip/hip_runtime.h>
#include <hip/hip_bf16.h>
#include <math.h>

// Problem constants
#define BATCH 4
#define SEQ   2048
#define CDIM  1024
#define NHEAD 16
#define HDIM  64
#define QKVN  3072
#define QSCALE 0.1803368801111244f   // 0.125 * log2(e); softmax done in exp2 domain

typedef float f32x4 __attribute__((ext_vector_type(4)));
typedef float f32x16 __attribute__((ext_vector_type(16)));
typedef short bf16x8 __attribute__((ext_vector_type(8)));
typedef short bf16x4 __attribute__((ext_vector_type(4)));
typedef int i32x2 __attribute__((ext_vector_type(2)));
typedef int i32x4 __attribute__((ext_vector_type(4)));

static __device__ __forceinline__ unsigned short f2bf(float f) {
    unsigned int u = __float_as_uint(f);
    u += 0x7FFF + ((u >> 16) & 1);   // RNE
    return (unsigned short)(u >> 16);
}
static __device__ __forceinline__ float bf2f(unsigned short u) {
    return __uint_as_float(((unsigned int)u) << 16);
}
static __device__ __forceinline__ unsigned int pk2bf(float lo, float hi) {
    __hip_bfloat162 h = __float22bfloat162_rn(make_float2(lo, hi));
    return *(unsigned int*)&h;
}
// 16-byte LDS read as two 8B halves (pitch-68 rows are only 8B aligned)
static __device__ __forceinline__ bf16x8 lds_read8(const unsigned short* p) {
    bf16x4 lo = *(const bf16x4*)p;
    bf16x4 hi = *(const bf16x4*)(p + 4);
    return __builtin_shufflevector(lo, hi, 0, 1, 2, 3, 4, 5, 6, 7);
}

// ---------------- consolidated prep: ctab + x->bf16 + both W transposes ------
static __device__ __forceinline__ void transpose_tile(
    const float* __restrict__ W, unsigned short* __restrict__ Wt,
    int K, int N, int bx, int by, unsigned short (*tile)[65], int tid) {
    const int n0 = bx * 64;
    const int k0 = by * 64;
    const int r = tid >> 4;
    const int c4 = (tid & 15) << 2;
    #pragma unroll
    for (int ii = 0; ii < 4; ii++) {
        int row = r + 16 * ii;
        float4 v = *(const float4*)&W[(size_t)(k0 + row) * N + n0 + c4];
        tile[c4 + 0][row] = f2bf(v.x);
        tile[c4 + 1][row] = f2bf(v.y);
        tile[c4 + 2][row] = f2bf(v.z);
        tile[c4 + 3][row] = f2bf(v.w);
    }
    __syncthreads();
    #pragma unroll
    for (int ii = 0; ii < 4; ii++) {
        int row = r + 16 * ii;
        ushort4 o;
        o.x = tile[row][c4 + 0];
        o.y = tile[row][c4 + 1];
        o.z = tile[row][c4 + 2];
        o.w = tile[row][c4 + 3];
        *(ushort4*)&Wt[(size_t)(n0 + row) * K + k0 + c4] = o;
    }
}

__global__ __launch_bounds__(256) void prep(
    const float* __restrict__ x, const float* __restrict__ W_qkv,
    const float* __restrict__ W_out, float2* __restrict__ ctab,
    unsigned short* __restrict__ xb, unsigned short* __restrict__ wqb,
    unsigned short* __restrict__ wob) {
    __shared__ unsigned short tile[64][65];
    const int blk = blockIdx.x;
    const int tid = threadIdx.x;
    if (blk < 8192) {
        // x fp32 -> xb bf16, 2,097,152 float4s
        const int i = blk * 256 + tid;
        float4 v = ((const float4*)x)[i];
        ushort4 o;
        o.x = f2bf(v.x); o.y = f2bf(v.y); o.z = f2bf(v.z); o.w = f2bf(v.w);
        ((ushort4*)xb)[i] = o;
    } else if (blk < 8448) {
        // RoPE table: ctab[t*32+dp] = (cos, sin), 65536 entries
        const int i = (blk - 8192) * 256 + tid;
        const int dp = i & 31;
        const int t = i >> 5;
        const float invf = powf(10000.0f, -((float)(2 * dp)) / 64.0f);
        float sv, cv;
        __sincosf((float)t * invf, &sv, &cv);
        ctab[i] = make_float2(cv, sv);
    } else if (blk < 9216) {
        // W_qkv [1024][3072] -> wqb [3072][1024], dim3(48,16)
        const int r = blk - 8448;
        transpose_tile(W_qkv, wqb, CDIM, QKVN, r % 48, r / 48, tile, tid);
    } else {
        // W_out [1024][1024] -> wob [1024][1024]^T, dim3(16,16)
        const int r = blk - 9216;
        transpose_tile(W_out, wob, CDIM, CDIM, r % 16, r / 16, tile, tid);
    }
}

#define GLDS(gp, lp) __builtin_amdgcn_global_load_lds(                       \
    (const __attribute__((address_space(1))) unsigned int*)(gp),             \
    (__attribute__((address_space(3))) unsigned int*)(lp), 16, 0, 0)

// ---------------- bf16 MFMA GEMM (BK=32, R9-proven): C = A @ Bt^T ------------
// Kept at the R7/R9-measured-best form: single-buffer, two barriers, natural
// grid order (R8 proved XCD stripes double FETCH; R8/R10 proved dbuf/BK=64
// without a register bound cost occupancy).
template <typename OUT>
__global__ __launch_bounds__(256) void gemm_bt_bf16(
    const unsigned short* __restrict__ A,
    const unsigned short* __restrict__ Bt,
    OUT* __restrict__ C, int M, int N, int K) {
    __shared__ unsigned short As[128 * 32];
    __shared__ unsigned short Bs[128 * 32];

    const int tid = threadIdx.x;
    const int wave = tid >> 6;
    const int lane = tid & 63;
    const int bm = blockIdx.y * 128;
    const int bn = blockIdx.x * 128;
    const int wm = (wave >> 1) * 64;
    const int wn = (wave & 1) * 64;

    const int srow = tid >> 2;
    const int scol = (((tid & 3) ^ ((tid >> 3) & 3)) << 3);   // swizzled global chunk
    const unsigned short* Ag0 = A + (size_t)(bm + srow) * K + scol;
    const unsigned short* Ag1 = A + (size_t)(bm + 64 + srow) * K + scol;
    const unsigned short* Bg0 = Bt + (size_t)(bn + srow) * K + scol;
    const unsigned short* Bg1 = Bt + (size_t)(bn + 64 + srow) * K + scol;
    char* AsW = (char*)As + wave * 1024;
    char* BsW = (char*)Bs + wave * 1024;

    const int fm = lane & 15;
    const int quad = lane >> 4;
    const int ck = (quad ^ ((fm >> 1) & 3)) << 3;   // swizzled read chunk

    f32x4 acc[4][4];
    #pragma unroll
    for (int i = 0; i < 4; i++)
        #pragma unroll
        for (int j = 0; j < 4; j++)
            acc[i][j] = (f32x4){0.f, 0.f, 0.f, 0.f};

    for (int k0 = 0; k0 < K; k0 += 32) {
        GLDS(Ag0 + k0, AsW);
        GLDS(Ag1 + k0, AsW + 4096);
        GLDS(Bg0 + k0, BsW);
        GLDS(Bg1 + k0, BsW + 4096);
        __syncthreads();

        bf16x8 af[4], bfr[4];
        #pragma unroll
        for (int i = 0; i < 4; i++)
            af[i] = *(const bf16x8*)&As[(wm + i * 16 + fm) * 32 + ck];
        #pragma unroll
        for (int j = 0; j < 4; j++)
            bfr[j] = *(const bf16x8*)&Bs[(wn + j * 16 + fm) * 32 + ck];
        #pragma unroll
        for (int i = 0; i < 4; i++)
            #pragma unroll
            for (int j = 0; j < 4; j++)
                acc[i][j] = __builtin_amdgcn_mfma_f32_16x16x32_bf16(
                    af[i], bfr[j], acc[i][j], 0, 0, 0);
        __syncthreads();
    }

    const int er = quad * 4;
    #pragma unroll
    for (int i = 0; i < 4; i++) {
        #pragma unroll
        for (int j = 0; j < 4; j++) {
            #pragma unroll
            for (int r = 0; r < 4; r++) {
                size_t off = (size_t)(bm + wm + i * 16 + er + r) * N + bn + wn + j * 16 + fm;
                if constexpr (sizeof(OUT) == 2)
                    C[off] = f2bf(acc[i][j][r]);
                else
                    C[off] = acc[i][j][r];
            }
        }
    }
}

// ---------------- fused qkv GEMM, BK=64 + pinned occupancy (R11) -------------
// R10 proved BK=64 math correct but let VGPR slip to 132 (over the 128 cliff
// -> 3 waves/SIMD) and occupancy halved. R11 = the clean A/B: BK=64 with
// __launch_bounds__(256,4) pinning VGPR<=128 -> 4 blocks/CU (LDS 32.8KB x4 =
// 131KB <= 160), same residency as the BK=32 baseline, HALF the barrier-drain
// events. If this is null at equal occupancy, the GEMM drain theory is
// falsified and the m97-structure is closed at its shape ceiling.
// Bank swizzle (verified R10, passed): slot sl of row r holds global chunk
// sl^(r&7); staging pre-permutes the per-lane GLOBAL chunk; reads use
// sl = (ks*4+quad)^(fm&7) -> 2 lanes/bank = free.
__global__ __launch_bounds__(256, 4) void gemm_qkv_fused(
    const unsigned short* __restrict__ A,     // xb [8192][1024]
    const unsigned short* __restrict__ Bt,    // wqb [3072][1024]
    const float2* __restrict__ ctab,          // [2048][32]
    unsigned short* __restrict__ Qg,
    unsigned short* __restrict__ Kg,
    unsigned short* __restrict__ Vtg) {
    __shared__ unsigned short SH[16384];      // loop: As=SH[0:8192), Bs=SH[8192:16384)
                                              // epilogue: [64][132] bf16 tile
    unsigned short* As = SH;
    unsigned short* Bs = SH + 8192;
    const int K = CDIM;

    const int tid = threadIdx.x;
    const int wave = tid >> 6;
    const int lane = tid & 63;
    const int bm = blockIdx.y * 128;
    const int bn = blockIdx.x * 128;
    const int wm = (wave >> 1) * 64;
    const int wn = (wave & 1) * 64;

    const int sr = tid >> 3;
    const int sc = ((tid & 7) ^ (sr & 7)) << 3;
    const unsigned short* Ag = A + (size_t)(bm + sr) * K + sc;
    const unsigned short* Bg = Bt + (size_t)(bn + sr) * K + sc;
    char* AsW = (char*)SH + wave * 1024;
    char* BsW = (char*)SH + 16384 + wave * 1024;   // byte offset of Bs

    const int fm = lane & 15;
    const int quad = lane >> 4;
    const int sl0 = ((quad ^ (fm & 7)) << 3);
    const int sl1 = (((4 + quad) ^ (fm & 7)) << 3);

    f32x4 acc[4][4];
    #pragma unroll
    for (int i = 0; i < 4; i++)
        #pragma unroll
        for (int j = 0; j < 4; j++)
            acc[i][j] = (f32x4){0.f, 0.f, 0.f, 0.f};

    for (int k0 = 0; k0 < K; k0 += 64) {
        GLDS(Ag + k0, AsW);
        GLDS(Ag + 32 * K + k0, AsW + 4096);
        GLDS(Ag + 64 * K + k0, AsW + 8192);
        GLDS(Ag + 96 * K + k0, AsW + 12288);
        GLDS(Bg + k0, BsW);
        GLDS(Bg + 32 * K + k0, BsW + 4096);
        GLDS(Bg + 64 * K + k0, BsW + 8192);
        GLDS(Bg + 96 * K + k0, BsW + 12288);
        __syncthreads();

        bf16x8 af[4], bfr[4];
        // ---- ks = 0 slice ----
        #pragma unroll
        for (int i = 0; i < 4; i++)
            af[i] = *(const bf16x8*)&As[(wm + i * 16 + fm) * 64 + sl0];
        #pragma unroll
        for (int j = 0; j < 4; j++)
            bfr[j] = *(const bf16x8*)&Bs[(wn + j * 16 + fm) * 64 + sl0];
        #pragma unroll
        for (int i = 0; i < 4; i++)
            #pragma unroll
            for (int j = 0; j < 4; j++)
                acc[i][j] = __builtin_amdgcn_mfma_f32_16x16x32_bf16(
                    af[i], bfr[j], acc[i][j], 0, 0, 0);
        // ---- ks = 1 slice ----
        #pragma unroll
        for (int i = 0; i < 4; i++)
            af[i] = *(const bf16x8*)&As[(wm + i * 16 + fm) * 64 + sl1];
        #pragma unroll
        for (int j = 0; j < 4; j++)
            bfr[j] = *(const bf16x8*)&Bs[(wn + j * 16 + fm) * 64 + sl1];
        #pragma unroll
        for (int i = 0; i < 4; i++)
            #pragma unroll
            for (int j = 0; j < 4; j++)
                acc[i][j] = __builtin_amdgcn_mfma_f32_16x16x32_bf16(
                    af[i], bfr[j], acc[i][j], 0, 0, 0);
        __syncthreads();
    }

    // ---------------- fused epilogue (unchanged from R7/R9) ----------------
    const int s = bn >> 10;                  // 0=q, 1=k, 2=v (128-col tile never straddles)
    const int hbase = (bn & 1023) >> 6;      // block covers heads hbase, hbase+1
    const int b = bm >> 11;                  // 128-row tile never straddles batch
    const int t0 = bm & 2047;

    #pragma unroll 1
    for (int pass = 0; pass < 2; pass++) {
        // waves whose rows are in this half write their acc tile to SH [64][132]
        if ((wave >> 1) == pass) {
            #pragma unroll
            for (int i = 0; i < 4; i++)
                #pragma unroll
                for (int j = 0; j < 4; j++)
                    #pragma unroll
                    for (int r = 0; r < 4; r++)
                        SH[(i * 16 + quad * 4 + r) * 132 + wn + j * 16 + fm] =
                            f2bf(acc[i][j][r]);
        }
        __syncthreads();

        if (s < 2) {
            unsigned short* dst = (s == 0) ? Qg : Kg;
            const float sc2 = (s == 0) ? QSCALE : 1.0f;
            #pragma unroll
            for (int it = 0; it < 16; it++) {
                const int idx = it * 256 + tid;      // 64 rows x 64 col-pairs
                const int row = idx >> 6;
                const int col = (idx & 63) << 1;
                const unsigned int pr = *(const unsigned int*)&SH[row * 132 + col];
                const float x0 = bf2f((unsigned short)pr);
                const float x1 = bf2f((unsigned short)(pr >> 16));
                const int t = t0 + pass * 64 + row;
                const int h = hbase + (col >> 6);
                const int d = col & 63;
                const float2 cs = ctab[t * 32 + (d >> 1)];
                const float r0 = (x0 * cs.x - x1 * cs.y) * sc2;
                const float r1 = (x1 * cs.x + x0 * cs.y) * sc2;
                *(unsigned int*)&dst[((size_t)(b * NHEAD + h) * SEQ + t) * HDIM + d] =
                    pk2bf(r0, r1);
            }
        } else {
            #pragma unroll
            for (int it = 0; it < 8; it++) {
                const int idx = it * 256 + tid;      // 128 cols x 16 t-chunks
                const int dcol = idx >> 4;
                const int tq = idx & 15;
                ushort4 o;
                o.x = SH[(tq * 4 + 0) * 132 + dcol];
                o.y = SH[(tq * 4 + 1) * 132 + dcol];
                o.z = SH[(tq * 4 + 2) * 132 + dcol];
                o.w = SH[(tq * 4 + 3) * 132 + dcol];
                const int h = hbase + (dcol >> 6);
                const int dl = dcol & 63;
                const int t = t0 + pass * 64 + tq * 4;
                *(ushort4*)&Vtg[((size_t)(b * NHEAD + h) * HDIM + dl) * SEQ + t] = o;
            }
        }
        __syncthreads();
    }
}

// ---------------- MFMA flash attention: in-register P (T12), 32x32 MFMAs ----
// R6 (passed): R0 residency (4 blocks/CU) + dbuf 1-barrier schedule +
// swapped-QK^T in-register softmax (cvt_pk + permlane32_swap, no Ps LDS).
__global__ __launch_bounds__(256, 4) void flash_attn_mfma(
    const unsigned short* __restrict__ Qg,
    const unsigned short* __restrict__ Kg,
    const unsigned short* __restrict__ Vtg,
    unsigned short* __restrict__ att) {
    __shared__ unsigned short Ks[2][64 * 68];   // [buf][key][d]
    __shared__ unsigned short Vt[2][64 * 68];   // [buf][d][key]

    const int tid = threadIdx.x;
    const int wave = tid >> 6;
    const int lane = tid & 63;
    const int l31 = lane & 31;
    const int hi = lane >> 5;
    const int wq = wave * 32;
    const int bh = blockIdx.x & 63;          // blk%8==bh%8 -> bh's blocks share an XCD
    const int qt = 15 - (blockIdx.x >> 6);   // heavy Q-tiles first
    const int b = bh >> 4, h = bh & 15;

    const int r_ld = tid >> 4;
    const int c4 = (tid & 15) << 2;

    const unsigned short* Kbase = Kg + (size_t)bh * SEQ * HDIM;
    const unsigned short* Vbase = Vtg + (size_t)bh * HDIM * SEQ;

    const int qrow = qt * 128 + wq + l31;    // this lane's q column

    // Q B-fragments (n=l31=q, k=d chunk dc*16 + hi*8): 4 x 16B from global
    bf16x8 bq[4];
    #pragma unroll
    for (int dc = 0; dc < 4; dc++)
        bq[dc] = *(const bf16x8*)&Qg[((size_t)bh * SEQ + qrow) * HDIM + dc * 16 + hi * 8];

    f32x16 O[2];
    #pragma unroll
    for (int nt = 0; nt < 2; nt++)
        #pragma unroll
        for (int r = 0; r < 16; r++) O[nt][r] = 0.f;
    float lsum = 0.f;

    const int jtop = 2 * qt + 1;

    // ---- prologue: stage tile 0 into buffer 0 ----
    ushort4 kreg[4], vreg[4];
    #pragma unroll
    for (int ii = 0; ii < 4; ii++) {
        const int row = r_ld + 16 * ii;
        kreg[ii] = *(const ushort4*)&Kbase[(size_t)row * HDIM + c4];
        vreg[ii] = *(const ushort4*)&Vbase[(size_t)row * SEQ + c4];
    }
    #pragma unroll
    for (int ii = 0; ii < 4; ii++) {
        const int row = r_ld + 16 * ii;
        *(ushort4*)&Ks[0][row * 68 + c4] = kreg[ii];
        *(ushort4*)&Vt[0][row * 68 + c4] = vreg[ii];
    }
    __syncthreads();

    int cur = 0;
    #pragma unroll 1
    for (int j = 0; j <= jtop; j++) {
        // (A) issue next tile's global loads now; consumed at (C) after compute
        if (j < jtop) {
            #pragma unroll
            for (int ii = 0; ii < 4; ii++) {
                const int row = r_ld + 16 * ii;
                kreg[ii] = *(const ushort4*)&Kbase[(size_t)((j + 1) * 64 + row) * HDIM + c4];
                vreg[ii] = *(const ushort4*)&Vbase[(size_t)row * SEQ + (j + 1) * 64 + c4];
            }
        }

        // (B) compute tile j from buffer cur
        const bool active = (j * 64) <= (qt * 128 + wq + 31);
        if (active) {
            const unsigned short* Kc = Ks[cur];
            const unsigned short* Vc = Vt[cur];
            const bool diag = (j * 64 + 63) > (qt * 128 + wq);

            #pragma unroll
            for (int kt = 0; kt < 2; kt++) {
                // ---- S^T = K Q^T : D[k][q], lane col q=l31 ----
                f32x16 sa;
                #pragma unroll
                for (int r = 0; r < 16; r++) sa[r] = 0.f;
                __builtin_amdgcn_s_setprio(1);
                #pragma unroll
                for (int dc = 0; dc < 4; dc++) {
                    bf16x8 ak = lds_read8(&Kc[(kt * 32 + l31) * 68 + dc * 16 + hi * 8]);
                    sa = __builtin_amdgcn_mfma_f32_32x32x16_bf16(ak, bq[dc], sa, 0, 0, 0);
                }
                __builtin_amdgcn_s_setprio(0);

                // ---- causal mask (diagonal tiles only): k_glob > q ----
                if (diag) {
                    const int kb = j * 64 + kt * 32 + 4 * hi;
                    #pragma unroll
                    for (int r = 0; r < 16; r++) {
                        const int kg = kb + (r & 3) + 8 * (r >> 2);
                        if (kg > qrow) sa[r] = -INFINITY;
                    }
                }

                // ---- P = exp2(S), per-lane row-sum partial, pack to bf16 ----
                float e[16];
                #pragma unroll
                for (int r = 0; r < 16; r++) {
                    e[r] = exp2f(sa[r]);
                    lsum += e[r];
                }
                unsigned int p32[8];
                #pragma unroll
                for (int v = 0; v < 8; v++)
                    p32[v] = pk2bf(e[2 * v], e[2 * v + 1]);

                // ---- permlane32_swap -> PV A-frags; O += P @ V ----
                #pragma unroll
                for (int c = 0; c < 2; c++) {
                    i32x2 s0 = __builtin_amdgcn_permlane32_swap(
                        (int)p32[4 * c + 0], (int)p32[4 * c + 2], false, false);
                    i32x2 s1 = __builtin_amdgcn_permlane32_swap(
                        (int)p32[4 * c + 1], (int)p32[4 * c + 3], false, false);
                    i32x4 pw = (i32x4){s0[0], s1[0], s0[1], s1[1]};
                    bf16x8 pa = *(bf16x8*)&pw;
                    __builtin_amdgcn_s_setprio(1);
                    #pragma unroll
                    for (int nt = 0; nt < 2; nt++) {
                        bf16x8 bv = lds_read8(&Vc[(nt * 32 + l31) * 68 + kt * 32 + c * 16 + hi * 8]);
                        O[nt] = __builtin_amdgcn_mfma_f32_32x32x16_bf16(pa, bv, O[nt], 0, 0, 0);
                    }
                    __builtin_amdgcn_s_setprio(0);
                }
            }
        }

        // (C) write tile j+1 into the idle buffer (vmcnt waits here, a full
        //     compute phase after issue)
        if (j < jtop) {
            const int nb = cur ^ 1;
            #pragma unroll
            for (int ii = 0; ii < 4; ii++) {
                const int row = r_ld + 16 * ii;
                *(ushort4*)&Ks[nb][row * 68 + c4] = kreg[ii];
                *(ushort4*)&Vt[nb][row * 68 + c4] = vreg[ii];
            }
        }

        // (D) one barrier per iteration
        __syncthreads();
        cur ^= 1;
    }

    // ---- epilogue: complete l (partner half), broadcast to O rows, store ----
    const float lfull = lsum + __shfl_xor(lsum, 32);
    const float inv = 1.0f / lfull;          // valid at lanes q and q+32
    #pragma unroll
    for (int r = 0; r < 16; r++) {
        const int qloc = (r & 3) + 8 * (r >> 2) + 4 * hi;   // O row within 32
        const float invr = __uint_as_float((unsigned int)__builtin_amdgcn_ds_bpermute(
            qloc * 4, (int)__float_as_uint(inv)));
        const int row = qt * 128 + wq + qloc;
        #pragma unroll
        for (int nt = 0; nt < 2; nt++)
            att[(size_t)(b * SEQ + row) * CDIM + h * HDIM + nt * 32 + l31] =
                f2bf(O[nt][r] * invr);
    }
}

extern "C" void kernel_launch(void* const* d_in, const int* in_sizes, int n_in,
                              void* d_out, int out_size, void* d_ws, size_t ws_size,
                              hipStream_t stream) {
    const float* x     = (const float*)d_in[0];
    const float* W_qkv = (const float*)d_in[1];
    const float* W_out = (const float*)d_in[2];
    float* out = (float*)d_out;

    const int M = BATCH * SEQ;   // 8192

    // workspace layout (~92 MB)
    float2* ctab = (float2*)d_ws;                               // 2048*32 float2
    unsigned short* xb   = (unsigned short*)(ctab + SEQ * 32);  // M*1024 bf16
    unsigned short* wqb  = xb + (size_t)M * CDIM;               // 3072*1024
    unsigned short* wob  = wqb + (size_t)CDIM * QKVN;           // 1024*1024
    unsigned short* attb = wob + (size_t)CDIM * CDIM;           // M*1024
    unsigned short* Qg   = attb + (size_t)M * CDIM;             // [bh][t][d]
    unsigned short* Kg   = Qg + (size_t)M * CDIM;
    unsigned short* Vtg  = Kg + (size_t)M * CDIM;               // [bh][d][t]

    // 1) consolidated prep: ctab + x->bf16 + W transposes (one launch)
    prep<<<9472, 256, 0, stream>>>(x, W_qkv, W_out, ctab, xb, wqb, wob);

    // 2) fused qkv GEMM (BK=64, occupancy-pinned, R11): writes Qg/Kg/Vtg
    gemm_qkv_fused<<<dim3(QKVN / 128, M / 128), 256, 0, stream>>>(
        xb, wqb, ctab, Qg, Kg, Vtg);

    // 3) MFMA flash attention: in-register P, 32x32 MFMAs, dbuf 1-barrier (R6)
    flash_attn_mfma<<<BATCH * NHEAD * (SEQ / 128), 256, 0, stream>>>(Qg, Kg, Vtg, attb);

    // 4) out = att @ W_out (BK=32 R9-proven form, fp32 out)
    gemm_bt_bf16<float><<<dim3(CDIM / 128, M / 128), 256, 0, stream>>>(
        attb, wob, out, M, CDIM, CDIM);
}

// Round 12
// 257.835 us; speedup vs baseline: 1.1551x; 1.0489x over previous
//
#include <hip/hip_runtime.h>
#include <hip/hip_bf16.h>
#include <math.h>

// Problem constants
#define BATCH 4
#define SEQ   2048
#define CDIM  1024
#define NHEAD 16
#define HDIM  64
#define QKVN  3072
#define QSCALE 0.1803368801111244f   // 0.125 * log2(e); softmax done in exp2 domain

typedef float f32x4 __attribute__((ext_vector_type(4)));
typedef float f32x16 __attribute__((ext_vector_type(16)));
typedef short bf16x8 __attribute__((ext_vector_type(8)));
typedef short bf16x4 __attribute__((ext_vector_type(4)));
typedef int i32x2 __attribute__((ext_vector_type(2)));
typedef int i32x4 __attribute__((ext_vector_type(4)));

static __device__ __forceinline__ unsigned short f2bf(float f) {
    unsigned int u = __float_as_uint(f);
    u += 0x7FFF + ((u >> 16) & 1);   // RNE
    return (unsigned short)(u >> 16);
}
static __device__ __forceinline__ float bf2f(unsigned short u) {
    return __uint_as_float(((unsigned int)u) << 16);
}
static __device__ __forceinline__ unsigned int pk2bf(float lo, float hi) {
    __hip_bfloat162 h = __float22bfloat162_rn(make_float2(lo, hi));
    return *(unsigned int*)&h;
}
// 16-byte LDS read as two 8B halves (pitch-68 rows are only 8B aligned)
static __device__ __forceinline__ bf16x8 lds_read8(const unsigned short* p) {
    bf16x4 lo = *(const bf16x4*)p;
    bf16x4 hi = *(const bf16x4*)(p + 4);
    return __builtin_shufflevector(lo, hi, 0, 1, 2, 3, 4, 5, 6, 7);
}

// ---------------- consolidated prep: ctab + x->bf16 + both W transposes ------
static __device__ __forceinline__ void transpose_tile(
    const float* __restrict__ W, unsigned short* __restrict__ Wt,
    int K, int N, int bx, int by, unsigned short (*tile)[65], int tid) {
    const int n0 = bx * 64;
    const int k0 = by * 64;
    const int r = tid >> 4;
    const int c4 = (tid & 15) << 2;
    #pragma unroll
    for (int ii = 0; ii < 4; ii++) {
        int row = r + 16 * ii;
        float4 v = *(const float4*)&W[(size_t)(k0 + row) * N + n0 + c4];
        tile[c4 + 0][row] = f2bf(v.x);
        tile[c4 + 1][row] = f2bf(v.y);
        tile[c4 + 2][row] = f2bf(v.z);
        tile[c4 + 3][row] = f2bf(v.w);
    }
    __syncthreads();
    #pragma unroll
    for (int ii = 0; ii < 4; ii++) {
        int row = r + 16 * ii;
        ushort4 o;
        o.x = tile[row][c4 + 0];
        o.y = tile[row][c4 + 1];
        o.z = tile[row][c4 + 2];
        o.w = tile[row][c4 + 3];
        *(ushort4*)&Wt[(size_t)(n0 + row) * K + k0 + c4] = o;
    }
}

__global__ __launch_bounds__(256) void prep(
    const float* __restrict__ x, const float* __restrict__ W_qkv,
    const float* __restrict__ W_out, float2* __restrict__ ctab,
    unsigned short* __restrict__ xb, unsigned short* __restrict__ wqb,
    unsigned short* __restrict__ wob) {
    __shared__ unsigned short tile[64][65];
    const int blk = blockIdx.x;
    const int tid = threadIdx.x;
    if (blk < 8192) {
        // x fp32 -> xb bf16, 2,097,152 float4s
        const int i = blk * 256 + tid;
        float4 v = ((const float4*)x)[i];
        ushort4 o;
        o.x = f2bf(v.x); o.y = f2bf(v.y); o.z = f2bf(v.z); o.w = f2bf(v.w);
        ((ushort4*)xb)[i] = o;
    } else if (blk < 8448) {
        // RoPE table: ctab[t*32+dp] = (cos, sin), 65536 entries
        const int i = (blk - 8192) * 256 + tid;
        const int dp = i & 31;
        const int t = i >> 5;
        const float invf = powf(10000.0f, -((float)(2 * dp)) / 64.0f);
        float sv, cv;
        __sincosf((float)t * invf, &sv, &cv);
        ctab[i] = make_float2(cv, sv);
    } else if (blk < 9216) {
        // W_qkv [1024][3072] -> wqb [3072][1024], dim3(48,16)
        const int r = blk - 8448;
        transpose_tile(W_qkv, wqb, CDIM, QKVN, r % 48, r / 48, tile, tid);
    } else {
        // W_out [1024][1024] -> wob [1024][1024]^T, dim3(16,16)
        const int r = blk - 9216;
        transpose_tile(W_out, wob, CDIM, CDIM, r % 16, r / 16, tile, tid);
    }
}

#define GLDS(gp, lp) __builtin_amdgcn_global_load_lds(                       \
    (const __attribute__((address_space(1))) unsigned int*)(gp),             \
    (__attribute__((address_space(3))) unsigned int*)(lp), 16, 0, 0)

// ---------------- bf16 MFMA GEMM, BK=64 + pinned occupancy ------------------
// R12: port of the R11-VALIDATED qkv change (BK=64 halves barrier-drain
// events; __launch_bounds__(256,4) pins VGPR<=128 so occupancy stays 4
// blocks/CU — R10 proved the unpinned version slips to 132 VGPR and halves
// occupancy). Bank swizzle (verified R10/R11): slot sl of row r holds global
// chunk sl^(r&7); reads use sl=(ks*4+quad)^(fm&7) -> 2 lanes/bank = free.
template <typename OUT>
__global__ __launch_bounds__(256, 4) void gemm_bt_bf16(
    const unsigned short* __restrict__ A,
    const unsigned short* __restrict__ Bt,
    OUT* __restrict__ C, int M, int N, int K) {
    __shared__ unsigned short As[128 * 64];
    __shared__ unsigned short Bs[128 * 64];

    const int tid = threadIdx.x;
    const int wave = tid >> 6;
    const int lane = tid & 63;
    const int bm = blockIdx.y * 128;
    const int bn = blockIdx.x * 128;
    const int wm = (wave >> 1) * 64;
    const int wn = (wave & 1) * 64;

    const int sr = tid >> 3;
    const int sc = ((tid & 7) ^ (sr & 7)) << 3;
    const unsigned short* Ag = A + (size_t)(bm + sr) * K + sc;
    const unsigned short* Bg = Bt + (size_t)(bn + sr) * K + sc;
    char* AsW = (char*)As + wave * 1024;
    char* BsW = (char*)Bs + wave * 1024;

    const int fm = lane & 15;
    const int quad = lane >> 4;
    const int sl0 = ((quad ^ (fm & 7)) << 3);        // ks=0 slot (elem offset)
    const int sl1 = (((4 + quad) ^ (fm & 7)) << 3);  // ks=1 slot

    f32x4 acc[4][4];
    #pragma unroll
    for (int i = 0; i < 4; i++)
        #pragma unroll
        for (int j = 0; j < 4; j++)
            acc[i][j] = (f32x4){0.f, 0.f, 0.f, 0.f};

    for (int k0 = 0; k0 < K; k0 += 64) {
        GLDS(Ag + k0, AsW);
        GLDS(Ag + 32 * K + k0, AsW + 4096);
        GLDS(Ag + 64 * K + k0, AsW + 8192);
        GLDS(Ag + 96 * K + k0, AsW + 12288);
        GLDS(Bg + k0, BsW);
        GLDS(Bg + 32 * K + k0, BsW + 4096);
        GLDS(Bg + 64 * K + k0, BsW + 8192);
        GLDS(Bg + 96 * K + k0, BsW + 12288);
        __syncthreads();

        bf16x8 af[4], bfr[4];
        // ---- ks = 0 slice ----
        #pragma unroll
        for (int i = 0; i < 4; i++)
            af[i] = *(const bf16x8*)&As[(wm + i * 16 + fm) * 64 + sl0];
        #pragma unroll
        for (int j = 0; j < 4; j++)
            bfr[j] = *(const bf16x8*)&Bs[(wn + j * 16 + fm) * 64 + sl0];
        #pragma unroll
        for (int i = 0; i < 4; i++)
            #pragma unroll
            for (int j = 0; j < 4; j++)
                acc[i][j] = __builtin_amdgcn_mfma_f32_16x16x32_bf16(
                    af[i], bfr[j], acc[i][j], 0, 0, 0);
        // ---- ks = 1 slice ----
        #pragma unroll
        for (int i = 0; i < 4; i++)
            af[i] = *(const bf16x8*)&As[(wm + i * 16 + fm) * 64 + sl1];
        #pragma unroll
        for (int j = 0; j < 4; j++)
            bfr[j] = *(const bf16x8*)&Bs[(wn + j * 16 + fm) * 64 + sl1];
        #pragma unroll
        for (int i = 0; i < 4; i++)
            #pragma unroll
            for (int j = 0; j < 4; j++)
                acc[i][j] = __builtin_amdgcn_mfma_f32_16x16x32_bf16(
                    af[i], bfr[j], acc[i][j], 0, 0, 0);
        __syncthreads();
    }

    const int er = quad * 4;
    #pragma unroll
    for (int i = 0; i < 4; i++) {
        #pragma unroll
        for (int j = 0; j < 4; j++) {
            #pragma unroll
            for (int r = 0; r < 4; r++) {
                size_t off = (size_t)(bm + wm + i * 16 + er + r) * N + bn + wn + j * 16 + fm;
                if constexpr (sizeof(OUT) == 2)
                    C[off] = f2bf(acc[i][j][r]);
                else
                    C[off] = acc[i][j][r];
            }
        }
    }
}

// ---------------- fused qkv GEMM, BK=64 + pinned occupancy (R11, proven) -----
__global__ __launch_bounds__(256, 4) void gemm_qkv_fused(
    const unsigned short* __restrict__ A,     // xb [8192][1024]
    const unsigned short* __restrict__ Bt,    // wqb [3072][1024]
    const float2* __restrict__ ctab,          // [2048][32]
    unsigned short* __restrict__ Qg,
    unsigned short* __restrict__ Kg,
    unsigned short* __restrict__ Vtg) {
    __shared__ unsigned short SH[16384];      // loop: As=SH[0:8192), Bs=SH[8192:16384)
                                              // epilogue: [64][132] bf16 tile
    unsigned short* As = SH;
    unsigned short* Bs = SH + 8192;
    const int K = CDIM;

    const int tid = threadIdx.x;
    const int wave = tid >> 6;
    const int lane = tid & 63;
    const int bm = blockIdx.y * 128;
    const int bn = blockIdx.x * 128;
    const int wm = (wave >> 1) * 64;
    const int wn = (wave & 1) * 64;

    const int sr = tid >> 3;
    const int sc = ((tid & 7) ^ (sr & 7)) << 3;
    const unsigned short* Ag = A + (size_t)(bm + sr) * K + sc;
    const unsigned short* Bg = Bt + (size_t)(bn + sr) * K + sc;
    char* AsW = (char*)SH + wave * 1024;
    char* BsW = (char*)SH + 16384 + wave * 1024;   // byte offset of Bs

    const int fm = lane & 15;
    const int quad = lane >> 4;
    const int sl0 = ((quad ^ (fm & 7)) << 3);
    const int sl1 = (((4 + quad) ^ (fm & 7)) << 3);

    f32x4 acc[4][4];
    #pragma unroll
    for (int i = 0; i < 4; i++)
        #pragma unroll
        for (int j = 0; j < 4; j++)
            acc[i][j] = (f32x4){0.f, 0.f, 0.f, 0.f};

    for (int k0 = 0; k0 < K; k0 += 64) {
        GLDS(Ag + k0, AsW);
        GLDS(Ag + 32 * K + k0, AsW + 4096);
        GLDS(Ag + 64 * K + k0, AsW + 8192);
        GLDS(Ag + 96 * K + k0, AsW + 12288);
        GLDS(Bg + k0, BsW);
        GLDS(Bg + 32 * K + k0, BsW + 4096);
        GLDS(Bg + 64 * K + k0, BsW + 8192);
        GLDS(Bg + 96 * K + k0, BsW + 12288);
        __syncthreads();

        bf16x8 af[4], bfr[4];
        // ---- ks = 0 slice ----
        #pragma unroll
        for (int i = 0; i < 4; i++)
            af[i] = *(const bf16x8*)&As[(wm + i * 16 + fm) * 64 + sl0];
        #pragma unroll
        for (int j = 0; j < 4; j++)
            bfr[j] = *(const bf16x8*)&Bs[(wn + j * 16 + fm) * 64 + sl0];
        #pragma unroll
        for (int i = 0; i < 4; i++)
            #pragma unroll
            for (int j = 0; j < 4; j++)
                acc[i][j] = __builtin_amdgcn_mfma_f32_16x16x32_bf16(
                    af[i], bfr[j], acc[i][j], 0, 0, 0);
        // ---- ks = 1 slice ----
        #pragma unroll
        for (int i = 0; i < 4; i++)
            af[i] = *(const bf16x8*)&As[(wm + i * 16 + fm) * 64 + sl1];
        #pragma unroll
        for (int j = 0; j < 4; j++)
            bfr[j] = *(const bf16x8*)&Bs[(wn + j * 16 + fm) * 64 + sl1];
        #pragma unroll
        for (int i = 0; i < 4; i++)
            #pragma unroll
            for (int j = 0; j < 4; j++)
                acc[i][j] = __builtin_amdgcn_mfma_f32_16x16x32_bf16(
                    af[i], bfr[j], acc[i][j], 0, 0, 0);
        __syncthreads();
    }

    // ---------------- fused epilogue (unchanged from R7/R9) ----------------
    const int s = bn >> 10;                  // 0=q, 1=k, 2=v (128-col tile never straddles)
    const int hbase = (bn & 1023) >> 6;      // block covers heads hbase, hbase+1
    const int b = bm >> 11;                  // 128-row tile never straddles batch
    const int t0 = bm & 2047;

    #pragma unroll 1
    for (int pass = 0; pass < 2; pass++) {
        // waves whose rows are in this half write their acc tile to SH [64][132]
        if ((wave >> 1) == pass) {
            #pragma unroll
            for (int i = 0; i < 4; i++)
                #pragma unroll
                for (int j = 0; j < 4; j++)
                    #pragma unroll
                    for (int r = 0; r < 4; r++)
                        SH[(i * 16 + quad * 4 + r) * 132 + wn + j * 16 + fm] =
                            f2bf(acc[i][j][r]);
        }
        __syncthreads();

        if (s < 2) {
            unsigned short* dst = (s == 0) ? Qg : Kg;
            const float sc2 = (s == 0) ? QSCALE : 1.0f;
            #pragma unroll
            for (int it = 0; it < 16; it++) {
                const int idx = it * 256 + tid;      // 64 rows x 64 col-pairs
                const int row = idx >> 6;
                const int col = (idx & 63) << 1;
                const unsigned int pr = *(const unsigned int*)&SH[row * 132 + col];
                const float x0 = bf2f((unsigned short)pr);
                const float x1 = bf2f((unsigned short)(pr >> 16));
                const int t = t0 + pass * 64 + row;
                const int h = hbase + (col >> 6);
                const int d = col & 63;
                const float2 cs = ctab[t * 32 + (d >> 1)];
                const float r0 = (x0 * cs.x - x1 * cs.y) * sc2;
                const float r1 = (x1 * cs.x + x0 * cs.y) * sc2;
                *(unsigned int*)&dst[((size_t)(b * NHEAD + h) * SEQ + t) * HDIM + d] =
                    pk2bf(r0, r1);
            }
        } else {
            #pragma unroll
            for (int it = 0; it < 8; it++) {
                const int idx = it * 256 + tid;      // 128 cols x 16 t-chunks
                const int dcol = idx >> 4;
                const int tq = idx & 15;
                ushort4 o;
                o.x = SH[(tq * 4 + 0) * 132 + dcol];
                o.y = SH[(tq * 4 + 1) * 132 + dcol];
                o.z = SH[(tq * 4 + 2) * 132 + dcol];
                o.w = SH[(tq * 4 + 3) * 132 + dcol];
                const int h = hbase + (dcol >> 6);
                const int dl = dcol & 63;
                const int t = t0 + pass * 64 + tq * 4;
                *(ushort4*)&Vtg[((size_t)(b * NHEAD + h) * HDIM + dl) * SEQ + t] = o;
            }
        }
        __syncthreads();
    }
}

// ---------------- MFMA flash attention: in-register P + MFMA row-sums -------
// R12: flash is VALU-bound (R11: VALUBusy 59-61 vs MfmaUtil 18.7). Shift the
// row-sum from the VALU to the idle MFMA pipe (R0's P@ones trick, re-derived
// for the swapped layout): lsum16 = mfma(pa, bones, lsum16) -> D[q][n] has
// every column equal to the row-sum, and its C-layout ROW MAPPING IS O's, so
// the epilogue needs NO shuffles (per-reg 1/lsum16[r] is correct in every
// lane). Deletes 32 v_add/iter + shfl_xor + 16 ds_bpermute; adds 4 MFMA/iter
// (16->20). P is bf16 in PV, so bf16 P@ones is exactly consistent (R0
// shipped this at the same absmax).
__global__ __launch_bounds__(256, 4) void flash_attn_mfma(
    const unsigned short* __restrict__ Qg,
    const unsigned short* __restrict__ Kg,
    const unsigned short* __restrict__ Vtg,
    unsigned short* __restrict__ att) {
    __shared__ unsigned short Ks[2][64 * 68];   // [buf][key][d]
    __shared__ unsigned short Vt[2][64 * 68];   // [buf][d][key]

    const int tid = threadIdx.x;
    const int wave = tid >> 6;
    const int lane = tid & 63;
    const int l31 = lane & 31;
    const int hi = lane >> 5;
    const int wq = wave * 32;
    const int bh = blockIdx.x & 63;          // blk%8==bh%8 -> bh's blocks share an XCD
    const int qt = 15 - (blockIdx.x >> 6);   // heavy Q-tiles first
    const int b = bh >> 4, h = bh & 15;

    const int r_ld = tid >> 4;
    const int c4 = (tid & 15) << 2;

    const unsigned short* Kbase = Kg + (size_t)bh * SEQ * HDIM;
    const unsigned short* Vbase = Vtg + (size_t)bh * HDIM * SEQ;

    const int qrow = qt * 128 + wq + l31;    // this lane's q column

    // Q B-fragments (n=l31=q, k=d chunk dc*16 + hi*8): 4 x 16B from global
    bf16x8 bq[4];
    #pragma unroll
    for (int dc = 0; dc < 4; dc++)
        bq[dc] = *(const bf16x8*)&Qg[((size_t)bh * SEQ + qrow) * HDIM + dc * 16 + hi * 8];

    // bf16 1.0 broadcast B-operand for the row-sum MFMA
    bf16x8 bones;
    #pragma unroll
    for (int z = 0; z < 8; z++) bones[z] = (short)0x3F80;

    f32x16 O[2], lsum16;
    #pragma unroll
    for (int nt = 0; nt < 2; nt++)
        #pragma unroll
        for (int r = 0; r < 16; r++) O[nt][r] = 0.f;
    #pragma unroll
    for (int r = 0; r < 16; r++) lsum16[r] = 0.f;

    const int jtop = 2 * qt + 1;

    // ---- prologue: stage tile 0 into buffer 0 ----
    ushort4 kreg[4], vreg[4];
    #pragma unroll
    for (int ii = 0; ii < 4; ii++) {
        const int row = r_ld + 16 * ii;
        kreg[ii] = *(const ushort4*)&Kbase[(size_t)row * HDIM + c4];
        vreg[ii] = *(const ushort4*)&Vbase[(size_t)row * SEQ + c4];
    }
    #pragma unroll
    for (int ii = 0; ii < 4; ii++) {
        const int row = r_ld + 16 * ii;
        *(ushort4*)&Ks[0][row * 68 + c4] = kreg[ii];
        *(ushort4*)&Vt[0][row * 68 + c4] = vreg[ii];
    }
    __syncthreads();

    int cur = 0;
    #pragma unroll 1
    for (int j = 0; j <= jtop; j++) {
        // (A) issue next tile's global loads now; consumed at (C) after compute
        if (j < jtop) {
            #pragma unroll
            for (int ii = 0; ii < 4; ii++) {
                const int row = r_ld + 16 * ii;
                kreg[ii] = *(const ushort4*)&Kbase[(size_t)((j + 1) * 64 + row) * HDIM + c4];
                vreg[ii] = *(const ushort4*)&Vbase[(size_t)row * SEQ + (j + 1) * 64 + c4];
            }
        }

        // (B) compute tile j from buffer cur
        const bool active = (j * 64) <= (qt * 128 + wq + 31);
        if (active) {
            const unsigned short* Kc = Ks[cur];
            const unsigned short* Vc = Vt[cur];
            const bool diag = (j * 64 + 63) > (qt * 128 + wq);

            #pragma unroll
            for (int kt = 0; kt < 2; kt++) {
                // ---- S^T = K Q^T : D[k][q], lane col q=l31 ----
                f32x16 sa;
                #pragma unroll
                for (int r = 0; r < 16; r++) sa[r] = 0.f;
                __builtin_amdgcn_s_setprio(1);
                #pragma unroll
                for (int dc = 0; dc < 4; dc++) {
                    bf16x8 ak = lds_read8(&Kc[(kt * 32 + l31) * 68 + dc * 16 + hi * 8]);
                    sa = __builtin_amdgcn_mfma_f32_32x32x16_bf16(ak, bq[dc], sa, 0, 0, 0);
                }
                __builtin_amdgcn_s_setprio(0);

                // ---- causal mask (diagonal tiles only): k_glob > q ----
                if (diag) {
                    const int kb = j * 64 + kt * 32 + 4 * hi;
                    #pragma unroll
                    for (int r = 0; r < 16; r++) {
                        const int kg = kb + (r & 3) + 8 * (r >> 2);
                        if (kg > qrow) sa[r] = -INFINITY;
                    }
                }

                // ---- P = exp2(S) packed straight to bf16 (no scalar sums) ----
                unsigned int p32[8];
                #pragma unroll
                for (int v = 0; v < 8; v++)
                    p32[v] = pk2bf(exp2f(sa[2 * v]), exp2f(sa[2 * v + 1]));

                // ---- permlane32_swap -> PV A-frags; O += P@V; l += P@1 ----
                #pragma unroll
                for (int c = 0; c < 2; c++) {
                    i32x2 s0 = __builtin_amdgcn_permlane32_swap(
                        (int)p32[4 * c + 0], (int)p32[4 * c + 2], false, false);
                    i32x2 s1 = __builtin_amdgcn_permlane32_swap(
                        (int)p32[4 * c + 1], (int)p32[4 * c + 3], false, false);
                    i32x4 pw = (i32x4){s0[0], s1[0], s0[1], s1[1]};
                    bf16x8 pa = *(bf16x8*)&pw;
                    __builtin_amdgcn_s_setprio(1);
                    lsum16 = __builtin_amdgcn_mfma_f32_32x32x16_bf16(pa, bones, lsum16, 0, 0, 0);
                    #pragma unroll
                    for (int nt = 0; nt < 2; nt++) {
                        bf16x8 bv = lds_read8(&Vc[(nt * 32 + l31) * 68 + kt * 32 + c * 16 + hi * 8]);
                        O[nt] = __builtin_amdgcn_mfma_f32_32x32x16_bf16(pa, bv, O[nt], 0, 0, 0);
                    }
                    __builtin_amdgcn_s_setprio(0);
                }
            }
        }

        // (C) write tile j+1 into the idle buffer (vmcnt waits here, a full
        //     compute phase after issue)
        if (j < jtop) {
            const int nb = cur ^ 1;
            #pragma unroll
            for (int ii = 0; ii < 4; ii++) {
                const int row = r_ld + 16 * ii;
                *(ushort4*)&Ks[nb][row * 68 + c4] = kreg[ii];
                *(ushort4*)&Vt[nb][row * 68 + c4] = vreg[ii];
            }
        }

        // (D) one barrier per iteration
        __syncthreads();
        cur ^= 1;
    }

    // ---- epilogue: lsum16 rows == O rows -> per-register normalize, store ----
    #pragma unroll
    for (int r = 0; r < 16; r++) {
        const float inv = 1.0f / lsum16[r];
        const int qloc = (r & 3) + 8 * (r >> 2) + 4 * hi;   // O row within 32
        const int row = qt * 128 + wq + qloc;
        #pragma unroll
        for (int nt = 0; nt < 2; nt++)
            att[(size_t)(b * SEQ + row) * CDIM + h * HDIM + nt * 32 + l31] =
                f2bf(O[nt][r] * inv);
    }
}

extern "C" void kernel_launch(void* const* d_in, const int* in_sizes, int n_in,
                              void* d_out, int out_size, void* d_ws, size_t ws_size,
                              hipStream_t stream) {
    const float* x     = (const float*)d_in[0];
    const float* W_qkv = (const float*)d_in[1];
    const float* W_out = (const float*)d_in[2];
    float* out = (float*)d_out;

    const int M = BATCH * SEQ;   // 8192

    // workspace layout (~92 MB)
    float2* ctab = (float2*)d_ws;                               // 2048*32 float2
    unsigned short* xb   = (unsigned short*)(ctab + SEQ * 32);  // M*1024 bf16
    unsigned short* wqb  = xb + (size_t)M * CDIM;               // 3072*1024
    unsigned short* wob  = wqb + (size_t)CDIM * QKVN;           // 1024*1024
    unsigned short* attb = wob + (size_t)CDIM * CDIM;           // M*1024
    unsigned short* Qg   = attb + (size_t)M * CDIM;             // [bh][t][d]
    unsigned short* Kg   = Qg + (size_t)M * CDIM;
    unsigned short* Vtg  = Kg + (size_t)M * CDIM;               // [bh][d][t]

    // 1) consolidated prep: ctab + x->bf16 + W transposes (one launch)
    prep<<<9472, 256, 0, stream>>>(x, W_qkv, W_out, ctab, xb, wqb, wob);

    // 2) fused qkv GEMM (BK=64, occupancy-pinned, R11-proven): writes Qg/Kg/Vtg
    gemm_qkv_fused<<<dim3(QKVN / 128, M / 128), 256, 0, stream>>>(
        xb, wqb, ctab, Qg, Kg, Vtg);

    // 3) MFMA flash attention: in-register P + MFMA row-sums (R12)
    flash_attn_mfma<<<BATCH * NHEAD * (SEQ / 128), 256, 0, stream>>>(Qg, Kg, Vtg, attb);

    // 4) out = att @ W_out (BK=64, occupancy-pinned, fp32 out)
    gemm_bt_bf16<float><<<dim3(CDIM / 128, M / 128), 256, 0, stream>>>(
        attb, wob, out, M, CDIM, CDIM);
}